// Round 9
// baseline (175.283 us; speedup 1.0000x reference)
//
#include <hip/hip_runtime.h>
#include <math.h>

// EKF over 2048 trajectories, T=512 serial steps. R9: ONE LANE PER
// TRAJECTORY (32 waves), all three decomposed 2-state filters (x, y, theta)
// in-lane. The three chains are independent -> intra-lane ILP fills the
// solo-wave stall slots that R5-R8's one-chain-per-lane layout exposed.
// No LDS, no shuffles, no flush phase:
//   - z: per-lane contiguous 12 B/step; 8-step tiles double-buffered in
//     registers (6 float4 loads/tile, issued a full tile ahead)
//   - loss: computed in-lane, buffered in regs, 2 float4 stores per tile
//     (one 64B line per lane per 2 tiles), fire-and-forget
//   - all filter constants wave-uniform -> SGPRs.
// Outer loop rolled (body fits L1I); 8-step tiles fully unrolled.

#define TILE 8

__device__ __forceinline__ float frcp(float x) { return __builtin_amdgcn_rcpf(x); }

// tanh(100*v) = 1 - 2/(exp2(c*v)+1); exp2 over/underflow round-trips
// correctly through rcp (inf->1, 0->-1), so no clamp.
__device__ __forceinline__ float tanh100(float v) {
    float e = exp2f(288.53900817779268f * v);
    return fmaf(-2.0f, frcp(e + 1.0f), 1.0f);
}

__global__ __launch_bounds__(64, 1) void ekf_kernel(
    const float* __restrict__ meas,        // (n_traj, T, 3)
    const float* __restrict__ init_state,  // (n_traj, 6)
    const float* __restrict__ dyna,        // (4,)
    const float* __restrict__ Qm,          // (6,6)
    const float* __restrict__ Rm,          // (3,3)
    const float* __restrict__ P0m,         // (6,6)
    float* __restrict__ out,               // (n_traj*T,)
    int n_traj, int T)
{
    int traj = blockIdx.x * 64 + threadIdx.x;
    if (traj >= n_traj) traj = n_traj - 1;   // dup lane writes same data: benign

    // ---- wave-uniform constants (SGPRs) ----
    const float DTc  = 1.0f / 120.0f;
    const float fric = dyna[0], damp = dyna[1];
    const float ca  = 1.0f - DTc * damp;
    const float cf  = DTc * fric;
    const float cb  = 100.0f * cf;
    const float ca2 = ca - cb;
    const float qx00 = Qm[0],  qxc = Qm[2],  qx22 = Qm[14];
    const float qy11 = Qm[7],  qyc = Qm[9],  qy33 = Qm[21];
    const float qt44 = Qm[28], qtc = Qm[29], qt55 = Qm[35];
    const float r0 = Rm[0], r1 = Rm[4], r2 = Rm[8];

    // ---- per-lane state ----
    float px00 = P0m[0],  px02 = P0m[2],  px22 = P0m[14];
    float py11 = P0m[7],  py13 = P0m[9],  py33 = P0m[21];
    float pt44 = P0m[28], pt45 = P0m[29], pt55 = P0m[35];

    const float2 s01 = *(const float2*)(init_state + 6 * traj);
    const float2 s23 = *(const float2*)(init_state + 6 * traj + 2);
    const float2 s45 = *(const float2*)(init_state + 6 * traj + 4);
    float X = s01.x, Y = s01.y, DX = s23.x, DY = s23.y, TH = s45.x, DTH = s45.y;

    const float* __restrict__ zp = meas + (size_t)traj * (size_t)(3 * T);
    float*       __restrict__ op = out  + (size_t)traj * (size_t)T;
    const int zlast = 3 * T - 4;             // last safe float4 base

    float za[3 * TILE], zb[3 * TILE], lv[TILE];

    // one EKF step for all three in-lane filters; z at zt[3t..3t+2]
    auto step = [&](const float* zt, int t) {
        const float z0 = zt[3 * t], z1 = zt[3 * t + 1], z2 = zt[3 * t + 2];
        const float tx = tanh100(DX);
        const float ty = tanh100(DY);
        // ---- X block ----
        const float ux   = fmaf(DTc, px22, px02);
        const float ppx0 = fmaf(DTc, px02 + ux, px00) + qx00;
        const float ax   = fmaf(cb, tx * tx, ca2);
        const float ppx2 = fmaf(ax, ux, qxc);
        const float ppxv = fmaf(ax * px22, ax, qx22);
        const float spx  = fmaf(DTc, DX, X);
        const float svx  = fmaf(-cf, tx, ca * DX);
        const float Sx   = ppx0 + r0;
        const float rsx  = frcp(Sx);
        const float yx   = z0 - spx;
        const float ryx  = rsx * yx;
        X  = fmaf(ppx0, ryx, spx);
        DX = fmaf(ppx2, ryx, svx);
        const float gx = r0 * rsx, kx = ppx2 * rsx;
        px00 = ppx0 * gx; px02 = ppx2 * gx; px22 = fmaf(-kx, ppx2, ppxv);
        const float mx = (yx * yx) * rsx;
        // ---- Y block ----
        const float uy   = fmaf(DTc, py33, py13);
        const float ppy0 = fmaf(DTc, py13 + uy, py11) + qy11;
        const float ay   = fmaf(cb, ty * ty, ca2);
        const float ppy2 = fmaf(ay, uy, qyc);
        const float ppyv = fmaf(ay * py33, ay, qy33);
        const float spy  = fmaf(DTc, DY, Y);
        const float svy  = fmaf(-cf, ty, ca * DY);
        const float Sy   = ppy0 + r1;
        const float rsy  = frcp(Sy);
        const float yy   = z1 - spy;
        const float ryy  = rsy * yy;
        Y  = fmaf(ppy0, ryy, spy);
        DY = fmaf(ppy2, ryy, svy);
        const float gy = r1 * rsy, ky = ppy2 * rsy;
        py11 = ppy0 * gy; py13 = ppy2 * gy; py33 = fmaf(-ky, ppy2, ppyv);
        const float my = (yy * yy) * rsy;
        // ---- THETA block (linear) ----
        const float ut   = fmaf(DTc, pt55, pt45);
        const float ppt0 = fmaf(DTc, pt45 + ut, pt44) + qt44;
        const float ppt2 = ut + qtc;
        const float pptv = pt55 + qt55;
        const float spt  = fmaf(DTc, DTH, TH);
        const float St   = ppt0 + r2;
        const float rst  = frcp(St);
        const float yt   = z2 - spt;
        const float ryt  = rst * yt;
        TH  = fmaf(ppt0, ryt, spt);
        DTH = fmaf(ppt2, ryt, DTH);
        const float gt = r2 * rst, kt = ppt2 * rst;
        pt44 = ppt0 * gt; pt45 = ppt2 * gt; pt55 = fmaf(-kt, ppt2, pptv);
        const float mt = (yt * yt) * rst;
        // ---- loss ----
        lv[t] = (Sx * Sy) * St + (mx + my + mt);
    };

    // ---- prologue: tile 0 into za ----
    #pragma unroll
    for (int c = 0; c < 6; ++c)
        *(float4*)&za[4 * c] = *(const float4*)(zp + 4 * c);

    #pragma unroll 1
    for (int kk = 0; kk < T / (2 * TILE); ++kk) {     // 32 iterations
        const int base = kk * (6 * TILE);              // float offset, tile 2kk

        // prefetch tile 2kk+1 -> zb (in flight across tile-A compute)
        #pragma unroll
        for (int c = 0; c < 6; ++c) {
            int o = base + 3 * TILE + 4 * c; o = (o <= zlast) ? o : zlast;
            *(float4*)&zb[4 * c] = *(const float4*)(zp + o);
        }

        // compute tile 2kk from za; store 8 losses (2x float4)
        #pragma unroll
        for (int t = 0; t < TILE; ++t) step(za, t);
        *(float4*)(op + kk * 2 * TILE)     = make_float4(lv[0], lv[1], lv[2], lv[3]);
        *(float4*)(op + kk * 2 * TILE + 4) = make_float4(lv[4], lv[5], lv[6], lv[7]);

        // prefetch tile 2kk+2 -> za (clamped on final iteration; unused)
        #pragma unroll
        for (int c = 0; c < 6; ++c) {
            int o = base + 6 * TILE + 4 * c; o = (o <= zlast) ? o : zlast;
            *(float4*)&za[4 * c] = *(const float4*)(zp + o);
        }

        // compute tile 2kk+1 from zb; store
        #pragma unroll
        for (int t = 0; t < TILE; ++t) step(zb, t);
        *(float4*)(op + kk * 2 * TILE + 8)  = make_float4(lv[0], lv[1], lv[2], lv[3]);
        *(float4*)(op + kk * 2 * TILE + 12) = make_float4(lv[4], lv[5], lv[6], lv[7]);
    }
}

extern "C" void kernel_launch(void* const* d_in, const int* in_sizes, int n_in,
                              void* d_out, int out_size, void* d_ws, size_t ws_size,
                              hipStream_t stream) {
    const float* meas = (const float*)d_in[0];
    const float* init_state = (const float*)d_in[1];
    const float* dyna = (const float*)d_in[2];
    const float* Qm  = (const float*)d_in[3];
    const float* Rm  = (const float*)d_in[4];
    const float* P0m = (const float*)d_in[5];
    float* out = (float*)d_out;

    const int n_traj = in_sizes[1] / 6;
    const int T = in_sizes[0] / (n_traj * 3);

    const int grid = (n_traj + 63) / 64;
    ekf_kernel<<<grid, 64, 0, stream>>>(meas, init_state, dyna, Qm, Rm, P0m,
                                        out, n_traj, T);
}

// Round 10
// 158.705 us; speedup vs baseline: 1.1045x; 1.1045x over previous
//
#include <hip/hip_runtime.h>
#include <math.h>

// EKF over 2048 trajectories, T=512 serial steps. ONE LANE PER TRAJECTORY
// (32 waves); all three decomposed 2-state filters (x, y, theta) in-lane —
// three independent dependency chains interleave to fill solo-wave stall
// slots (R7/R8 showed one-chain-per-lane is chain-latency bound at ~310
// cy/step regardless of instruction count).
//
// R10 vs R9: R9's float arrays + lambda pointer defeated SROA -> scratch
// spill (VGPR=52 for >56 live floats). Now all tile data lives in NAMED
// float4 variables (never address-taken), 8-step tiles hand-unrolled with
// compile-time component selection, loss written from a float4. Zero LDS,
// zero DS ops, zero memory ops inside the step chain.
//
// tanh chain shortened: w = 1/(exp2(c*v)+1);  1-tanh^2 = 4w(1-w);
// -cf*tanh = 2cf*w - cf.  (exp2 over/underflow round-trips correctly:
// e=inf -> w=0 -> tanh=+1 side; e=0 -> w=1 -> tanh=-1 side.)

#define CEXP 288.53900817779268f   // 200 * log2(e)

__device__ __forceinline__ float frcp(float x) { return __builtin_amdgcn_rcpf(x); }

// One EKF step for all three in-lane filters. z components are compile-time
// register selects; LT is an lvalue (float4 component) receiving the loss.
#define STEP(z0, z1, z2, LT) do {                                          \
    const float eX = exp2f(CEXP * DX);                                     \
    const float eY = exp2f(CEXP * DY);                                     \
    const float wX = frcp(eX + 1.0f);                                      \
    const float wY = frcp(eY + 1.0f);                                      \
    const float wwX = fmaf(wX, -wX, wX);                                   \
    const float wwY = fmaf(wY, -wY, wY);                                   \
    const float aX = fmaf(m4cb, wwX, ca);                                  \
    const float aY = fmaf(m4cb, wwY, ca);                                  \
    const float uX = fmaf(DTc, px22, px02);                                \
    const float uY = fmaf(DTc, py33, py13);                                \
    const float uT = fmaf(DTc, pt55, pt45);                                \
    const float p0X = fmaf(DTc, px02 + uX, px00) + qx00;                   \
    const float p0Y = fmaf(DTc, py13 + uY, py11) + qy11;                   \
    const float p0T = fmaf(DTc, pt45 + uT, pt44) + qt44;                   \
    const float p2X = fmaf(aX, uX, qxc);                                   \
    const float p2Y = fmaf(aY, uY, qyc);                                   \
    const float p2T = uT + qtc;                                            \
    const float pvX = fmaf(aX * px22, aX, qx22);                           \
    const float pvY = fmaf(aY * py33, aY, qy33);                           \
    const float pvT = pt55 + qt55;                                         \
    const float spX = fmaf(DTc, DX, X);                                    \
    const float spY = fmaf(DTc, DY, Y);                                    \
    const float spT = fmaf(DTc, DTH, TH);                                  \
    const float svX = fmaf(cf2, wX, fmaf(ca, DX, mcf));                    \
    const float svY = fmaf(cf2, wY, fmaf(ca, DY, mcf));                    \
    const float SX = p0X + r0, SY = p0Y + r1, ST = p0T + r2;               \
    const float rsX = frcp(SX), rsY = frcp(SY), rsT = frcp(ST);            \
    const float yX = (z0) - spX, yY = (z1) - spY, yT = (z2) - spT;         \
    const float ryX = rsX * yX, ryY = rsY * yY, ryT = rsT * yT;            \
    X   = fmaf(p0X, ryX, spX);  DX  = fmaf(p2X, ryX, svX);                 \
    Y   = fmaf(p0Y, ryY, spY);  DY  = fmaf(p2Y, ryY, svY);                 \
    TH  = fmaf(p0T, ryT, spT);  DTH = fmaf(p2T, ryT, DTH);                 \
    const float gX = r0 * rsX, gY = r1 * rsY, gT = r2 * rsT;               \
    const float kX = p2X * rsX, kY = p2Y * rsY, kT = p2T * rsT;            \
    px00 = p0X * gX; px02 = p2X * gX; px22 = fmaf(-kX, p2X, pvX);          \
    py11 = p0Y * gY; py13 = p2Y * gY; py33 = fmaf(-kY, p2Y, pvY);          \
    pt44 = p0T * gT; pt45 = p2T * gT; pt55 = fmaf(-kT, p2T, pvT);          \
    LT = fmaf(SX * SY, ST,                                                 \
              fmaf(yX * yX, rsX, fmaf(yY * yY, rsY, (yT * yT) * rsT)));    \
} while (0)

__global__ __launch_bounds__(64) void ekf_kernel(
    const float* __restrict__ meas,        // (n_traj, T, 3)
    const float* __restrict__ init_state,  // (n_traj, 6)
    const float* __restrict__ dyna,        // (4,)
    const float* __restrict__ Qm,          // (6,6)
    const float* __restrict__ Rm,          // (3,3)
    const float* __restrict__ P0m,         // (6,6)
    float* __restrict__ out,               // (n_traj*T,)
    int n_traj, int T)
{
    int traj = blockIdx.x * 64 + threadIdx.x;
    if (traj >= n_traj) traj = n_traj - 1;   // dup lane rewrites same data

    // ---- wave-uniform constants (SGPRs) ----
    const float DTc  = 1.0f / 120.0f;
    const float fric = dyna[0], damp = dyna[1];
    const float ca   = 1.0f - DTc * damp;
    const float cf   = DTc * fric;
    const float mcf  = -cf;
    const float cf2  = 2.0f * cf;
    const float m4cb = -400.0f * cf;         // -4 * (100*cf)
    const float qx00 = Qm[0],  qxc = Qm[2],  qx22 = Qm[14];
    const float qy11 = Qm[7],  qyc = Qm[9],  qy33 = Qm[21];
    const float qt44 = Qm[28], qtc = Qm[29], qt55 = Qm[35];
    const float r0 = Rm[0], r1 = Rm[4], r2 = Rm[8];

    // ---- per-lane filter state ----
    float px00 = P0m[0],  px02 = P0m[2],  px22 = P0m[14];
    float py11 = P0m[7],  py13 = P0m[9],  py33 = P0m[21];
    float pt44 = P0m[28], pt45 = P0m[29], pt55 = P0m[35];

    const float2 s01 = *(const float2*)(init_state + 6 * traj);
    const float2 s23 = *(const float2*)(init_state + 6 * traj + 2);
    const float2 s45 = *(const float2*)(init_state + 6 * traj + 4);
    float X = s01.x, Y = s01.y, DX = s23.x, DY = s23.y, TH = s45.x, DTH = s45.y;

    // meas per-traj base: traj*3T floats = 6144 B (16B aligned); out: 2048 B
    const float4* __restrict__ zp4 = (const float4*)(meas + (size_t)traj * (size_t)(3 * T));
    float4*       __restrict__ op4 = (float4*)(out + (size_t)traj * (size_t)T);
    const int z4max = (3 * T) / 4 - 1;       // 383

    float4 A0, A1, A2, A3, A4, A5;           // current 8-step tile (24 floats)
    float4 B0, B1, B2, B3, B4, B5;           // next 8-step tile
    float4 L;                                // 4 losses

    // prologue: tile 0
    A0 = zp4[0]; A1 = zp4[1]; A2 = zp4[2];
    A3 = zp4[3]; A4 = zp4[4]; A5 = zp4[5];

    const int NI = T / 16;                   // 32 iterations, 16 steps each
    #pragma unroll 1
    for (int kk = 0; kk < NI; ++kk) {
        const int ib = kk * 12;              // float4 base of tile pair

        // prefetch tile B (steps 8..15) — never OOB (ib+11 <= 383)
        B0 = zp4[ib + 6];  B1 = zp4[ib + 7];  B2 = zp4[ib + 8];
        B3 = zp4[ib + 9];  B4 = zp4[ib + 10]; B5 = zp4[ib + 11];

        // ---- 8 steps from A ----
        STEP(A0.x, A0.y, A0.z, L.x);
        STEP(A0.w, A1.x, A1.y, L.y);
        STEP(A1.z, A1.w, A2.x, L.z);
        STEP(A2.y, A2.z, A2.w, L.w);
        op4[kk * 4 + 0] = L;
        STEP(A3.x, A3.y, A3.z, L.x);
        STEP(A3.w, A4.x, A4.y, L.y);
        STEP(A4.z, A4.w, A5.x, L.z);
        STEP(A5.y, A5.z, A5.w, L.w);
        op4[kk * 4 + 1] = L;

        // prefetch next pair's tile A (clamped on final iteration; unused)
        const int ia = ib + 12;
        A0 = zp4[min(ia + 0, z4max)];
        A1 = zp4[min(ia + 1, z4max)];
        A2 = zp4[min(ia + 2, z4max)];
        A3 = zp4[min(ia + 3, z4max)];
        A4 = zp4[min(ia + 4, z4max)];
        A5 = zp4[min(ia + 5, z4max)];

        // ---- 8 steps from B ----
        STEP(B0.x, B0.y, B0.z, L.x);
        STEP(B0.w, B1.x, B1.y, L.y);
        STEP(B1.z, B1.w, B2.x, L.z);
        STEP(B2.y, B2.z, B2.w, L.w);
        op4[kk * 4 + 2] = L;
        STEP(B3.x, B3.y, B3.z, L.x);
        STEP(B3.w, B4.x, B4.y, L.y);
        STEP(B4.z, B4.w, B5.x, L.z);
        STEP(B5.y, B5.z, B5.w, L.w);
        op4[kk * 4 + 3] = L;
    }
}

extern "C" void kernel_launch(void* const* d_in, const int* in_sizes, int n_in,
                              void* d_out, int out_size, void* d_ws, size_t ws_size,
                              hipStream_t stream) {
    const float* meas = (const float*)d_in[0];
    const float* init_state = (const float*)d_in[1];
    const float* dyna = (const float*)d_in[2];
    const float* Qm  = (const float*)d_in[3];
    const float* Rm  = (const float*)d_in[4];
    const float* P0m = (const float*)d_in[5];
    float* out = (float*)d_out;

    const int n_traj = in_sizes[1] / 6;
    const int T = in_sizes[0] / (n_traj * 3);

    const int grid = (n_traj + 63) / 64;
    ekf_kernel<<<grid, 64, 0, stream>>>(meas, init_state, dyna, Qm, Rm, P0m,
                                        out, n_traj, T);
}